// Round 4
// baseline (256.901 us; speedup 1.0000x reference)
//
#include <hip/hip_runtime.h>

// Problem constants (B, L, D, H) = (16, 512, 128, 8)
#define B_  16
#define L_  512
#define D_  128
#define H_  8
#define HD_ 1024   // H*D
#define NH_ 128    // H*B
#define M_  8192   // B*L

typedef unsigned short u16;
typedef __attribute__((ext_vector_type(8))) short s16x8;   // 8 bf16 = 4 VGPRs
typedef __attribute__((ext_vector_type(4))) float f32x4;   // MFMA accumulator

// ---------- bf16 helpers ----------
__device__ __forceinline__ float bf2f(u16 u) {
    union { unsigned u; float f; } x; x.u = ((unsigned)u) << 16; return x.f;
}
__device__ __forceinline__ u16 f2bf(float f) {
    unsigned u = __float_as_uint(f);
    return (u16)((u + 0x7FFFu + ((u >> 16) & 1u)) >> 16);   // RNE
}

// ---------------------------------------------------------------
// MFMA bt-core: C(64x64) = A(64xK) @ B(64xK)^T for one wave.
// A/B operand layout: row = lane&15, k = (lane>>4)*8 + j  (16B contiguous)
// C/D: col = lane&15, row = (lane>>4)*4 + reg   (m89/m91-verified)
// ---------------------------------------------------------------
__device__ __forceinline__ void mfma_bt64(const u16* __restrict__ A, int lda,
                                          const u16* __restrict__ B, int ldb,
                                          int K, int lane, f32x4 acc[4][4]) {
    const int mr = lane & 15, quad = lane >> 4;
    for (int k0 = 0; k0 < K; k0 += 32) {
        s16x8 av[4], bv[4];
#pragma unroll
        for (int i = 0; i < 4; i++)
            av[i] = *(const s16x8*)(A + (size_t)(i * 16 + mr) * lda + k0 + quad * 8);
#pragma unroll
        for (int j = 0; j < 4; j++)
            bv[j] = *(const s16x8*)(B + (size_t)(j * 16 + mr) * ldb + k0 + quad * 8);
#pragma unroll
        for (int i = 0; i < 4; i++)
#pragma unroll
            for (int j = 0; j < 4; j++)
                acc[i][j] = __builtin_amdgcn_mfma_f32_16x16x32_bf16(av[i], bv[j], acc[i][j], 0, 0, 0);
    }
}

// ---------------------------------------------------------------
// K0: detect float dtype (fp32 vs packed bf16) + mask dtype (i32 vs u8).
// ---------------------------------------------------------------
__global__ void k0_detect(const unsigned int* __restrict__ pad,
                          const unsigned int* __restrict__ xw,
                          int* __restrict__ flags) {
    __shared__ int sMask, sCnt;
    if (threadIdx.x == 0) { sMask = 0; sCnt = 0; }
    __syncthreads();
    int bad = 0;
#pragma unroll
    for (int i = 0; i < 4; i++) {
        unsigned u = pad[threadIdx.x * 4 + i];
        bad |= (u > 1u) ? 1 : 0;
    }
    int cnt = 0;
#pragma unroll
    for (int i = 0; i < 16; i++) {
        unsigned w = xw[threadIdx.x * 16 + i];
        unsigned e = (w >> 7) & 0xFFu;
        cnt += (e >= 100u && e <= 131u) ? 1 : 0;
    }
    if (bad) atomicOr(&sMask, 1);
    atomicAdd(&sCnt, cnt);
    __syncthreads();
    if (threadIdx.x == 0) {
        flags[0] = (sCnt > 2048) ? 1 : 0;   // 1 => floats are bf16
        flags[1] = sMask;                   // 1 => mask is uint8
    }
}

// ---------------------------------------------------------------
// Kprep_conv: normalize all float inputs to bf16 in ws.
// ---------------------------------------------------------------
#define PREP_TOT 1576064
__global__ __launch_bounds__(256) void kprep_conv(
    const void* x, const void* Wq, const void* bq, const void* Wk, const void* bk,
    const void* Wv, const void* bv, const void* Wo, const void* bo,
    const int* __restrict__ flags,
    u16* xb, u16* Wqb, u16* Wkb, u16* Wvb, u16* Wob,
    u16* bqb, u16* bkb, u16* bvb, u16* bob) {
    int gid = blockIdx.x * 256 + threadIdx.x;
    if (gid >= PREP_TOT) return;
    const int dt = flags[0];
    const void* src; u16* dst; int off;
    if      (gid < 1048576) { src = x;  dst = xb;  off = gid; }
    else if (gid < 1179648) { src = Wq; dst = Wqb; off = gid - 1048576; }
    else if (gid < 1310720) { src = Wk; dst = Wkb; off = gid - 1179648; }
    else if (gid < 1441792) { src = Wv; dst = Wvb; off = gid - 1310720; }
    else if (gid < 1572864) { src = Wo; dst = Wob; off = gid - 1441792; }
    else if (gid < 1573888) { src = bq; dst = bqb; off = gid - 1572864; }
    else if (gid < 1574912) { src = bk; dst = bkb; off = gid - 1573888; }
    else if (gid < 1575936) { src = bv; dst = bvb; off = gid - 1574912; }
    else                    { src = bo; dst = bob; off = gid - 1575936; }
    dst[off] = dt ? ((const u16*)src)[off] : f2bf(((const float*)src)[off]);
}

// ---------------------------------------------------------------
// Kprep_mask: pack pad_mask into bitmask [16][512][16 u32 words].
// ---------------------------------------------------------------
__global__ __launch_bounds__(256) void kprep_mask(const void* __restrict__ pad,
                                                  const int* __restrict__ flags,
                                                  unsigned* __restrict__ mb) {
    int w = blockIdx.x * 256 + threadIdx.x;     // < 131072
    size_t base = (size_t)w * 32;
    unsigned m = 0;
    if (flags[1]) {
        const unsigned char* p = (const unsigned char*)pad;
#pragma unroll
        for (int b = 0; b < 32; b++) m |= (p[base + b] ? 1u : 0u) << b;
    } else {
        const int* p = (const int*)pad;
#pragma unroll
        for (int b = 0; b < 32; b++) m |= (p[base + b] ? 1u : 0u) << b;
    }
    mb[w] = m;
}

// ---------------------------------------------------------------
// K1: QKV projection via MFMA.  y = x @ W^T + b.
// q,k head-major [n][l][d]; v TRANSPOSED [n][d][l] (unscaled).
// grid (8 heads, 64 m-tiles, 3), 256 threads.
// ---------------------------------------------------------------
__global__ __launch_bounds__(256) void k1_proj(
    const u16* __restrict__ xb,
    const u16* __restrict__ Wqb, const u16* __restrict__ Wkb, const u16* __restrict__ Wvb,
    const u16* __restrict__ bqb, const u16* __restrict__ bkb, const u16* __restrict__ bvb,
    u16* __restrict__ qb, u16* __restrict__ kb, u16* __restrict__ vtb) {
    const int h  = blockIdx.x;
    const int m0 = blockIdx.y * 128;
    const int z  = blockIdx.z;
    const u16* W    = (z == 0) ? Wqb : (z == 1) ? Wkb : Wvb;
    const u16* bias = (z == 0) ? bqb : (z == 1) ? bkb : bvb;

    const int lane = threadIdx.x & 63, wave = threadIdx.x >> 6;
    const int wr = wave >> 1, wc = wave & 1;
    const int mr = lane & 15, quad = lane >> 4;

    f32x4 acc[4][4];
#pragma unroll
    for (int i = 0; i < 4; i++)
#pragma unroll
        for (int j = 0; j < 4; j++) acc[i][j] = (f32x4){0.f, 0.f, 0.f, 0.f};

    mfma_bt64(xb + (size_t)(m0 + wr * 64) * D_, D_,
              W + (size_t)(h * 128 + wc * 64) * D_, D_, D_, lane, acc);

    __shared__ __align__(16) u16 T[128][136];   // 136 pad: quad stride = 16 banks (2-way, free)
#pragma unroll
    for (int i = 0; i < 4; i++)
#pragma unroll
        for (int j = 0; j < 4; j++) {
            int col = wc * 64 + j * 16 + mr;
            float bv_ = bf2f(bias[h * 128 + col]);
#pragma unroll
            for (int r = 0; r < 4; r++)
                T[wr * 64 + i * 16 + quad * 4 + r][col] = f2bf(acc[i][j][r] + bv_);
        }
    __syncthreads();

    const int bb = m0 >> 9, l0 = m0 & 511;
    const int t = threadIdx.x;
    if (z < 2) {
        u16* out = z ? kb : qb;
        int row = t >> 1, c0 = (t & 1) * 64;
        u16* dst = out + ((size_t)(h * B_ + bb) * L_ + l0 + row) * D_ + c0;
#pragma unroll
        for (int c = 0; c < 64; c += 8)
            *(uint4*)(dst + c) = *(const uint4*)&T[row][c0 + c];
    } else {
        int d = t >> 1, lc0 = (t & 1) * 64;
        u16* dst = vtb + ((size_t)(h * B_ + bb) * D_ + d) * L_ + l0 + lc0;
#pragma unroll
        for (int c = 0; c < 64; c += 8) {
            u16 tmp[8];
#pragma unroll
            for (int s = 0; s < 8; s++) tmp[s] = T[lc0 + c + s][d];
            *(uint4*)(dst + c) = *(const uint4*)tmp;
        }
    }
}

// ---------------------------------------------------------------
// K2a: linv[n,k] = 1/sum_q exp(mask? -1e9 : qk * rs).  Nothing else stored.
// grid (4 k-strips, 128 n), 256 threads.  Mask bits staged in LDS.
// ---------------------------------------------------------------
__global__ __launch_bounds__(256) void k2a_linv(
    const u16* __restrict__ qb, const u16* __restrict__ kb,
    const unsigned* __restrict__ mbits, float* __restrict__ linv) {
    const int kstrip = blockIdx.x * 128;
    const int n   = blockIdx.y;
    const int bb  = n & (B_ - 1);
    const int lane = threadIdx.x & 63, wave = threadIdx.x >> 6;
    const int wr = wave >> 1, wc = wave & 1;
    const int mr = lane & 15, quad = lane >> 4;
    const float rs = 0.08838834764831845f;   // 1/sqrt(128)

    __shared__ unsigned mw[2048];            // [q 512][4 words of this strip]
    __shared__ float CS[2][128];
#pragma unroll
    for (int s = 0; s < 8; s++) {
        int idx = threadIdx.x * 8 + s;
        int q = idx >> 2, lw = idx & 3;
        mw[idx] = mbits[((size_t)(bb << 9) + q) * 16 + (blockIdx.x << 2) + lw];
    }
    __syncthreads();

    const u16* Abase = qb + (size_t)n * L_ * D_;
    const u16* Bbase = kb + (size_t)n * L_ * D_ + (size_t)(kstrip + wc * 64) * D_;

    float colsum[4] = {0.f, 0.f, 0.f, 0.f};
    for (int qt = 0; qt < 4; qt++) {
        f32x4 acc[4][4];
#pragma unroll
        for (int i = 0; i < 4; i++)
#pragma unroll
            for (int j = 0; j < 4; j++) acc[i][j] = (f32x4){0.f, 0.f, 0.f, 0.f};
        mfma_bt64(Abase + (size_t)(qt * 128 + wr * 64) * D_, D_, Bbase, D_, D_, lane, acc);
#pragma unroll
        for (int i = 0; i < 4; i++)
#pragma unroll
            for (int j = 0; j < 4; j++) {
                const int lw = wc * 2 + (j >> 1);
                const int bit = (j & 1) * 16 + mr;
#pragma unroll
                for (int r = 0; r < 4; r++) {
                    int q = qt * 128 + wr * 64 + i * 16 + quad * 4 + r;
                    unsigned w = mw[(q << 2) + lw];
                    if (!((w >> bit) & 1u))
                        colsum[j] += __expf(acc[i][j][r] * rs);
                }
            }
    }
#pragma unroll
    for (int j = 0; j < 4; j++) {
        colsum[j] += __shfl_xor(colsum[j], 16);
        colsum[j] += __shfl_xor(colsum[j], 32);
    }
    if (quad == 0) {
#pragma unroll
        for (int j = 0; j < 4; j++) CS[wr][wc * 64 + j * 16 + mr] = colsum[j];
    }
    __syncthreads();
    if (threadIdx.x < 128)
        linv[(size_t)n * L_ + kstrip + threadIdx.x] =
            1.0f / (CS[0][threadIdx.x] + CS[1][threadIdx.x]);
}

// ---------------------------------------------------------------
// K2b: fused attention.  Per (n, 128-q-tile): loop 4 k-tiles, recompute
// e = exp(qk*rs)*linv (masked->0) into LDS, MFMA against V^T fragments,
// accumulate att[q,d] in registers.  Score matrix never hits global.
// grid (4 q-tiles, 128 n), 256 threads.
// ---------------------------------------------------------------
__global__ __launch_bounds__(256) void k2b_attn(
    const u16* __restrict__ qb, const u16* __restrict__ kb,
    const u16* __restrict__ vtb, const unsigned* __restrict__ mbits,
    const float* __restrict__ linv, u16* __restrict__ att) {
    const int qtile = blockIdx.x * 128;
    const int n  = blockIdx.y;
    const int bb = n & (B_ - 1);
    const int lane = threadIdx.x & 63, wave = threadIdx.x >> 6;
    const int wr = wave >> 1, wc = wave & 1;
    const int mr = lane & 15, quad = lane >> 4;
    const float rs = 0.08838834764831845f;

    __shared__ __align__(16) u16 eS[128][136];  // 272B rows: 16B-aligned, 2-way banks
    __shared__ unsigned mwq[2048];              // [q 128][16 words]
    __shared__ float linvS[512];
#pragma unroll
    for (int s = 0; s < 8; s++) {
        int idx = threadIdx.x * 8 + s;
        int q = idx >> 4, w = idx & 15;
        mwq[idx] = mbits[((size_t)(bb << 9) + qtile + q) * 16 + w];
    }
    if (threadIdx.x < 128)
        *(float4*)&linvS[threadIdx.x * 4] = *(const float4*)&linv[(size_t)n * L_ + threadIdx.x * 4];
    __syncthreads();

    const u16* qn = qb + (size_t)n * L_ * D_;
    const u16* kn = kb + (size_t)n * L_ * D_;
    const u16* vn = vtb + (size_t)n * D_ * L_;

    f32x4 att_acc[4][4];
#pragma unroll
    for (int i = 0; i < 4; i++)
#pragma unroll
        for (int j = 0; j < 4; j++) att_acc[i][j] = (f32x4){0.f, 0.f, 0.f, 0.f};

    for (int kt = 0; kt < 4; kt++) {
        // --- QK^T for this 128x128 tile ---
        f32x4 qk[4][4];
#pragma unroll
        for (int i = 0; i < 4; i++)
#pragma unroll
            for (int j = 0; j < 4; j++) qk[i][j] = (f32x4){0.f, 0.f, 0.f, 0.f};
        mfma_bt64(qn + (size_t)(qtile + wr * 64) * D_, D_,
                  kn + (size_t)(kt * 128 + wc * 64) * D_, D_, D_, lane, qk);

        // --- mask + exp + linv -> bf16 e-tile in LDS ---
#pragma unroll
        for (int i = 0; i < 4; i++)
#pragma unroll
            for (int j = 0; j < 4; j++) {
                const int widx = kt * 4 + wc * 2 + (j >> 1);
                const int bit = (j & 1) * 16 + mr;
                const int kl = wc * 64 + j * 16 + mr;
                const float lv = linvS[kt * 128 + kl];
#pragma unroll
                for (int r = 0; r < 4; r++) {
                    int ql = wr * 64 + i * 16 + quad * 4 + r;
                    unsigned w = mwq[(ql << 4) + widx];
                    float e = ((w >> bit) & 1u) ? 0.f : __expf(qk[i][j][r] * rs) * lv;
                    eS[ql][kl] = f2bf(e);
                }
            }
        __syncthreads();

        // --- PV: att_acc += e(128x128) @ vt-tile^T ---
#pragma unroll
        for (int kk = 0; kk < 4; kk++) {
            s16x8 av[4], bv[4];
#pragma unroll
            for (int i = 0; i < 4; i++)
                av[i] = *(const s16x8*)&eS[wr * 64 + i * 16 + mr][kk * 32 + quad * 8];
#pragma unroll
            for (int j = 0; j < 4; j++)
                bv[j] = *(const s16x8*)(vn + (size_t)(wc * 64 + j * 16 + mr) * L_
                                        + kt * 128 + kk * 32 + quad * 8);
#pragma unroll
            for (int i = 0; i < 4; i++)
#pragma unroll
                for (int j = 0; j < 4; j++)
                    att_acc[i][j] = __builtin_amdgcn_mfma_f32_16x16x32_bf16(av[i], bv[j], att_acc[i][j], 0, 0, 0);
        }
        __syncthreads();
    }

    // --- epilogue: bounce through LDS (reuse eS), coalesced stores ---
#pragma unroll
    for (int i = 0; i < 4; i++)
#pragma unroll
        for (int j = 0; j < 4; j++) {
            int col = wc * 64 + j * 16 + mr;
#pragma unroll
            for (int r = 0; r < 4; r++)
                eS[wr * 64 + i * 16 + quad * 4 + r][col] = f2bf(att_acc[i][j][r]);
        }
    __syncthreads();
    int t = threadIdx.x, row = t >> 1, c0 = (t & 1) * 64;
    u16* dst = att + ((size_t)n * L_ + qtile + row) * D_ + c0;
#pragma unroll
    for (int c = 0; c < 64; c += 8)
        *(uint4*)(dst + c) = *(const uint4*)&eS[row][c0 + c];
}

// ---------------------------------------------------------------
// K5: out = att_flat[8192][1024] @ Wo[128][1024]^T + bo.
// grid (2 n-halves, 128 m-tiles), 128 threads (2 waves splitting K),
// LDS fp32 reduction.  dt-switched output.
// ---------------------------------------------------------------
__global__ __launch_bounds__(128) void k5_out(
    const u16* __restrict__ att, const u16* __restrict__ Wob,
    const u16* __restrict__ bob, const int* __restrict__ flags,
    void* __restrict__ out) {
    const int dt = flags[0];
    const int n0 = blockIdx.x * 64;
    const int m0 = blockIdx.y * 64;
    const int lane = threadIdx.x & 63, wk = threadIdx.x >> 6;
    const int mr = lane & 15, quad = lane >> 4;

    f32x4 acc[4][4];
#pragma unroll
    for (int i = 0; i < 4; i++)
#pragma unroll
        for (int j = 0; j < 4; j++) acc[i][j] = (f32x4){0.f, 0.f, 0.f, 0.f};

    mfma_bt64(att + (size_t)m0 * HD_ + wk * 512, HD_,
              Wob + (size_t)n0 * HD_ + wk * 512, HD_, 512, lane, acc);

    __shared__ __align__(16) float Tf[64][68];
    if (wk == 0) {
#pragma unroll
        for (int i = 0; i < 4; i++)
#pragma unroll
            for (int j = 0; j < 4; j++)
#pragma unroll
                for (int r = 0; r < 4; r++)
                    Tf[i * 16 + quad * 4 + r][j * 16 + mr] = acc[i][j][r];
    }
    __syncthreads();
    if (wk == 1) {
#pragma unroll
        for (int i = 0; i < 4; i++)
#pragma unroll
            for (int j = 0; j < 4; j++)
#pragma unroll
                for (int r = 0; r < 4; r++)
                    Tf[i * 16 + quad * 4 + r][j * 16 + mr] += acc[i][j][r];
    }
    __syncthreads();

    int t = threadIdx.x, row = t >> 1, h0 = (t & 1) * 32;
    size_t base = (size_t)(m0 + row) * D_ + n0 + h0;
    if (dt) {
        u16* o = (u16*)out;
#pragma unroll
        for (int c = 0; c < 32; c += 8) {
            u16 tmp[8];
#pragma unroll
            for (int s = 0; s < 8; s++)
                tmp[s] = f2bf(Tf[row][h0 + c + s] + bf2f(bob[n0 + h0 + c + s]));
            *(uint4*)(o + base + c) = *(const uint4*)tmp;
        }
    } else {
        float* o = (float*)out;
#pragma unroll
        for (int c = 0; c < 32; c += 4) {
            float4 v;
            v.x = Tf[row][h0 + c + 0] + bf2f(bob[n0 + h0 + c + 0]);
            v.y = Tf[row][h0 + c + 1] + bf2f(bob[n0 + h0 + c + 1]);
            v.z = Tf[row][h0 + c + 2] + bf2f(bob[n0 + h0 + c + 2]);
            v.w = Tf[row][h0 + c + 3] + bf2f(bob[n0 + h0 + c + 3]);
            *(float4*)(o + base + c) = v;
        }
    }
}

// ---------------------------------------------------------------
extern "C" void kernel_launch(void* const* d_in, const int* in_sizes, int n_in,
                              void* d_out, int out_size, void* d_ws, size_t ws_size,
                              hipStream_t stream) {
    (void)in_sizes; (void)n_in; (void)out_size; (void)ws_size;
    const void* x  = d_in[0];
    const void* Wq = d_in[1]; const void* bq = d_in[2];
    const void* Wk = d_in[3]; const void* bk = d_in[4];
    const void* Wv = d_in[5]; const void* bv = d_in[6];
    const void* Wo = d_in[7]; const void* bo = d_in[8];
    const void* pad = d_in[9];

    char* p = (char*)d_ws;
    auto alloc = [&](size_t bytes) { char* r = p; p += (bytes + 255) & ~(size_t)255; return r; };
    int*  flags = (int*)alloc(256);
    u16*  xb   = (u16*)alloc(2097152);
    u16*  Wqb  = (u16*)alloc(262144);
    u16*  Wkb  = (u16*)alloc(262144);
    u16*  Wvb  = (u16*)alloc(262144);
    u16*  Wob  = (u16*)alloc(262144);
    u16*  bqb  = (u16*)alloc(2048);
    u16*  bkb  = (u16*)alloc(2048);
    u16*  bvb  = (u16*)alloc(2048);
    u16*  bob  = (u16*)alloc(256);
    unsigned* mbits = (unsigned*)alloc(524288);
    float* linv = (float*)alloc(262144);
    u16*  qb   = (u16*)alloc(16777216);
    u16*  kb   = (u16*)alloc(16777216);
    u16*  vtb  = (u16*)alloc(16777216);
    u16*  att  = (u16*)alloc(2097152);

    k0_detect<<<1, 256, 0, stream>>>((const unsigned*)pad, (const unsigned*)x, flags);
    kprep_conv<<<(PREP_TOT + 255) / 256, 256, 0, stream>>>(
        x, Wq, bq, Wk, bk, Wv, bv, Wo, bo, flags,
        xb, Wqb, Wkb, Wvb, Wob, bqb, bkb, bvb, bob);
    kprep_mask<<<512, 256, 0, stream>>>(pad, flags, mbits);
    k1_proj<<<dim3(8, 64, 3), 256, 0, stream>>>(
        xb, Wqb, Wkb, Wvb, bqb, bkb, bvb, qb, kb, vtb);
    k2a_linv<<<dim3(4, NH_), 256, 0, stream>>>(qb, kb, mbits, linv);
    k2b_attn<<<dim3(4, NH_), 256, 0, stream>>>(qb, kb, vtb, mbits, linv, att);
    k5_out<<<dim3(2, 128), 128, 0, stream>>>(att, Wob, bob, flags, d_out);
}